// Round 6
// baseline (576.168 us; speedup 1.0000x reference)
//
#include <hip/hip_runtime.h>

#define N_NODES 100000
#define N_EDGES 3200000
#define D_FEAT 128
#define HIDDEN 16
#define NCLS 8

#define NBKT 512            // dst buckets
#define BSZ  196            // nodes per bucket (512*196 = 100352 >= 100000)
#define NSLICE 4            // edge-slice blocks per bucket
#define CHUNK 8192          // edges per hist/fill block
#define NCHUNK 391          // 391*8192 >= 3.2M
#define TOTH (NBKT * NCHUNK)   // 200192 = 782*256 exactly
#define NBS1 (TOTH / 256)      // 782

// -------- workspace layout (32-bit words) --------
// deg  (uint)  [0, N)
// dis  (float) [N, 2N)
// hist (uint)  [2N, +TOTH)
// bsum (uint)  [+1024)
// rec  (uint)  [+E)            (src<<8)|dst_local, bucketed by dst
// agg1 (float) [+16N)          fp32 accumulator, self-loop init
// hd1b (uint)  [+8N)           bf16x2-packed dis*(x@W1)   [N][8]  = 3.2 MB
// agg2 (float) [+8N)
// hd2b (uint)  [+4N)           bf16x2-packed layer2 msg   [N][4]  = 1.6 MB

__device__ __forceinline__ unsigned bf16rn(float x) {
    unsigned u = __float_as_uint(x);
    return (u + 0x7FFFu + ((u >> 16) & 1u)) >> 16;
}
__device__ __forceinline__ unsigned pack2(float a, float b) {
    return bf16rn(a) | (bf16rn(b) << 16);
}

__global__ void k_zero_deg(unsigned* __restrict__ deg) {
    int i = blockIdx.x * blockDim.x + threadIdx.x;
    if (i < N_NODES) deg[i] = 0u;
}

__global__ __launch_bounds__(256) void k_hist(const int* __restrict__ dst,
                                              unsigned* __restrict__ hist) {
    __shared__ unsigned h[NBKT];
    int tid = threadIdx.x;
    h[tid] = 0u; h[tid + 256] = 0u;
    __syncthreads();
    int base = blockIdx.x * CHUNK;
    #pragma unroll
    for (int it = 0; it < CHUNK / 256; ++it) {
        int e = base + it * 256 + tid;
        if (e < N_EDGES) atomicAdd(&h[dst[e] / BSZ], 1u);
    }
    __syncthreads();
    hist[(unsigned)tid * NCHUNK + blockIdx.x] = h[tid];
    hist[(unsigned)(tid + 256) * NCHUNK + blockIdx.x] = h[tid + 256];
}

__global__ void k_scan1(unsigned* __restrict__ a, unsigned* __restrict__ bsum) {
    __shared__ unsigned s[256];
    int tid = threadIdx.x;
    int i = blockIdx.x * 256 + tid;
    unsigned v = a[i];
    s[tid] = v; __syncthreads();
    for (int off = 1; off < 256; off <<= 1) {
        unsigned t = (tid >= off) ? s[tid - off] : 0u;
        __syncthreads();
        s[tid] += t;
        __syncthreads();
    }
    a[i] = s[tid] - v;
    if (tid == 255) bsum[blockIdx.x] = s[255];
}

__global__ void k_scan2(unsigned* __restrict__ bsum) {
    __shared__ unsigned s[1024];
    int tid = threadIdx.x;
    unsigned v = (tid < NBS1) ? bsum[tid] : 0u;
    s[tid] = v; __syncthreads();
    for (int off = 1; off < 1024; off <<= 1) {
        unsigned t = (tid >= off) ? s[tid - off] : 0u;
        __syncthreads();
        s[tid] += t;
        __syncthreads();
    }
    bsum[tid] = s[tid] - v;
}

__global__ void k_scan3(unsigned* __restrict__ a, const unsigned* __restrict__ bsum) {
    int i = blockIdx.x * blockDim.x + threadIdx.x;
    a[i] += bsum[i >> 8];
}

__global__ __launch_bounds__(256) void k_fill(const int* __restrict__ src,
                                              const int* __restrict__ dst,
                                              const unsigned* __restrict__ hist,
                                              unsigned* __restrict__ rec) {
    __shared__ unsigned cur[NBKT];
    int tid = threadIdx.x;
    cur[tid]       = hist[(unsigned)tid * NCHUNK + blockIdx.x];
    cur[tid + 256] = hist[(unsigned)(tid + 256) * NCHUNK + blockIdx.x];
    __syncthreads();
    int base = blockIdx.x * CHUNK;
    #pragma unroll
    for (int it = 0; it < CHUNK / 256; ++it) {
        int e = base + it * 256 + tid;
        if (e < N_EDGES) {
            int d = dst[e];
            int b = d / BSZ;
            unsigned p = atomicAdd(&cur[b], 1u);
            rec[p] = ((unsigned)src[e] << 8) | (unsigned)(d - b * BSZ);
        }
    }
}

__global__ __launch_bounds__(256) void k_deg(const unsigned* __restrict__ hist,
                                             const unsigned* __restrict__ rec,
                                             unsigned* __restrict__ deg) {
    __shared__ unsigned cnt[BSZ];
    int tid = threadIdx.x;
    int bkt = blockIdx.x >> 2, slice = blockIdx.x & 3;
    int node0 = bkt * BSZ;
    int nn = N_NODES - node0; if (nn > BSZ) nn = BSZ;
    if (nn <= 0) return;
    for (int n = tid; n < nn; n += 256) cnt[n] = 0u;
    __syncthreads();
    unsigned start = hist[(unsigned)bkt * NCHUNK];
    unsigned end = (bkt == NBKT - 1) ? N_EDGES : hist[(unsigned)(bkt + 1) * NCHUNK];
    for (unsigned e = start + slice * 256 + tid; e < end; e += 1024)
        atomicAdd(&cnt[rec[e] & 255u], 1u);
    __syncthreads();
    for (int n = tid; n < nn; n += 256)
        if (cnt[n]) atomicAdd(&deg[node0 + n], cnt[n]);
}

__global__ void k_disk(const unsigned* __restrict__ deg, float* __restrict__ dis) {
    int i = blockIdx.x * blockDim.x + threadIdx.x;
    if (i < N_NODES) dis[i] = rsqrtf((float)(deg[i] + 1u));
}

// agg1 = dis*(x@W1) fp32 (self-loop init); hd1b = same, bf16x2 packed
__global__ __launch_bounds__(256) void k_gemm1(const float* __restrict__ x,
                                               const float* __restrict__ W1,
                                               const float* __restrict__ dis,
                                               float* __restrict__ agg1,
                                               unsigned* __restrict__ hd1b) {
    __shared__ float sW[D_FEAT * HIDDEN];
    __shared__ float sx[64][132];
    int tid = threadIdx.x;
    for (int t = tid; t < D_FEAT * HIDDEN; t += 256) sW[t] = W1[t];

    int node0 = blockIdx.x * 64;
    #pragma unroll
    for (int it = 0; it < 8; ++it) {
        int lin = it * 256 + tid;
        int r   = lin >> 5;
        int c4  = lin & 31;
        int row = node0 + r;
        float4 v = make_float4(0.f, 0.f, 0.f, 0.f);
        if (row < N_NODES)
            v = *(const float4*)(x + (size_t)row * D_FEAT + c4 * 4);
        *(float4*)(&sx[r][c4 * 4]) = v;
    }
    __syncthreads();

    int lr   = tid >> 2;
    int node = node0 + lr;
    int f0   = (tid & 3) * 4;
    if (node >= N_NODES) return;

    float a0 = 0.f, a1 = 0.f, a2 = 0.f, a3 = 0.f;
    #pragma unroll
    for (int k = 0; k < D_FEAT; ++k) {
        float xv = sx[lr][k];
        a0 += xv * sW[k * HIDDEN + f0 + 0];
        a1 += xv * sW[k * HIDDEN + f0 + 1];
        a2 += xv * sW[k * HIDDEN + f0 + 2];
        a3 += xv * sW[k * HIDDEN + f0 + 3];
    }
    float s = dis[node];
    float4 o = make_float4(a0 * s, a1 * s, a2 * s, a3 * s);
    *(float4*)(agg1 + (size_t)node * HIDDEN + f0) = o;
    uint2 p = make_uint2(pack2(o.x, o.y), pack2(o.z, o.w));
    *(uint2*)(hd1b + (size_t)node * 8 + (f0 >> 1)) = p;
}

// layer1 gather from bf16 hd1b (L2-resident): LDS partials -> global atomic combine
__global__ __launch_bounds__(256) void k_agg1(const unsigned* __restrict__ hist,
                                              const unsigned* __restrict__ rec,
                                              const unsigned* __restrict__ hd1b,
                                              float* __restrict__ agg1) {
    __shared__ float acc[BSZ][HIDDEN + 1];
    int tid = threadIdx.x;
    int bkt = blockIdx.x >> 2, slice = blockIdx.x & 3;
    int node0 = bkt * BSZ;
    int nn = N_NODES - node0; if (nn > BSZ) nn = BSZ;
    if (nn <= 0) return;
    for (int t = tid; t < BSZ * (HIDDEN + 1); t += 256) ((float*)acc)[t] = 0.f;
    __syncthreads();

    unsigned start = hist[(unsigned)bkt * NCHUNK];
    unsigned end = (bkt == NBKT - 1) ? N_EDGES : hist[(unsigned)(bkt + 1) * NCHUNK];
    int j2 = tid & 7, rr = tid >> 3;        // 32 edge slots x 8 pair-lanes
    int jf = j2 * 2;
    unsigned e = start + (unsigned)(slice * 32 + rr);
    for (; e + 384u < end; e += 512u) {     // 4 independent packed gathers
        unsigned r0 = rec[e], r1 = rec[e + 128u], r2 = rec[e + 256u], r3 = rec[e + 384u];
        unsigned p0 = hd1b[(size_t)(r0 >> 8) * 8 + j2];
        unsigned p1 = hd1b[(size_t)(r1 >> 8) * 8 + j2];
        unsigned p2 = hd1b[(size_t)(r2 >> 8) * 8 + j2];
        unsigned p3 = hd1b[(size_t)(r3 >> 8) * 8 + j2];
        atomicAdd(&acc[r0 & 255u][jf],     __uint_as_float(p0 << 16));
        atomicAdd(&acc[r0 & 255u][jf + 1], __uint_as_float(p0 & 0xFFFF0000u));
        atomicAdd(&acc[r1 & 255u][jf],     __uint_as_float(p1 << 16));
        atomicAdd(&acc[r1 & 255u][jf + 1], __uint_as_float(p1 & 0xFFFF0000u));
        atomicAdd(&acc[r2 & 255u][jf],     __uint_as_float(p2 << 16));
        atomicAdd(&acc[r2 & 255u][jf + 1], __uint_as_float(p2 & 0xFFFF0000u));
        atomicAdd(&acc[r3 & 255u][jf],     __uint_as_float(p3 << 16));
        atomicAdd(&acc[r3 & 255u][jf + 1], __uint_as_float(p3 & 0xFFFF0000u));
    }
    for (; e < end; e += 128u) {
        unsigned r = rec[e];
        unsigned p = hd1b[(size_t)(r >> 8) * 8 + j2];
        atomicAdd(&acc[r & 255u][jf],     __uint_as_float(p << 16));
        atomicAdd(&acc[r & 255u][jf + 1], __uint_as_float(p & 0xFFFF0000u));
    }
    __syncthreads();
    for (int t = tid; t < nn * HIDDEN; t += 256) {
        float v = acc[t >> 4][t & 15];
        if (v != 0.f) atomicAdd(&agg1[(size_t)node0 * HIDDEN + t], v);
    }
}

// epilogue 1: h = relu(dis*agg1 + b1); msg2 = dis*(h @ W2) -> agg2 fp32 + hd2b bf16
__global__ __launch_bounds__(256) void k_epi1(const float* __restrict__ agg1,
                                              const float* __restrict__ dis,
                                              const float* __restrict__ b1,
                                              const float* __restrict__ W2,
                                              float* __restrict__ agg2,
                                              unsigned* __restrict__ hd2b) {
    __shared__ float sW2[HIDDEN * NCLS];
    __shared__ float sb1[HIDDEN];
    int tid = threadIdx.x;
    if (tid < HIDDEN * NCLS) sW2[tid] = W2[tid];
    if (tid < HIDDEN)        sb1[tid] = b1[tid];
    __syncthreads();
    int i = blockIdx.x * 256 + tid;
    if (i >= N_NODES) return;
    float dv = dis[i];
    float h[HIDDEN];
    const float4* ap = (const float4*)(agg1 + (size_t)i * HIDDEN);
    #pragma unroll
    for (int q = 0; q < 4; ++q) {
        float4 a = ap[q];
        h[q * 4 + 0] = fmaxf(dv * a.x + sb1[q * 4 + 0], 0.f);
        h[q * 4 + 1] = fmaxf(dv * a.y + sb1[q * 4 + 1], 0.f);
        h[q * 4 + 2] = fmaxf(dv * a.z + sb1[q * 4 + 2], 0.f);
        h[q * 4 + 3] = fmaxf(dv * a.w + sb1[q * 4 + 3], 0.f);
    }
    float o[NCLS];
    #pragma unroll
    for (int k = 0; k < NCLS; ++k) o[k] = 0.f;
    #pragma unroll
    for (int m = 0; m < HIDDEN; ++m) {
        float hv = h[m];
        #pragma unroll
        for (int k = 0; k < NCLS; ++k) o[k] += hv * sW2[m * NCLS + k];
    }
    #pragma unroll
    for (int k = 0; k < NCLS; ++k) o[k] *= dv;
    ((float4*)(agg2 + (size_t)i * NCLS))[0] = make_float4(o[0], o[1], o[2], o[3]);
    ((float4*)(agg2 + (size_t)i * NCLS))[1] = make_float4(o[4], o[5], o[6], o[7]);
    uint4 pk = make_uint4(pack2(o[0], o[1]), pack2(o[2], o[3]),
                          pack2(o[4], o[5]), pack2(o[6], o[7]));
    *(uint4*)(hd2b + (size_t)i * 4) = pk;
}

// layer2 gather from bf16 hd2b (L2-resident)
__global__ __launch_bounds__(256) void k_agg2(const unsigned* __restrict__ hist,
                                              const unsigned* __restrict__ rec,
                                              const unsigned* __restrict__ hd2b,
                                              float* __restrict__ agg2) {
    __shared__ float acc[BSZ][NCLS + 1];
    int tid = threadIdx.x;
    int bkt = blockIdx.x >> 2, slice = blockIdx.x & 3;
    int node0 = bkt * BSZ;
    int nn = N_NODES - node0; if (nn > BSZ) nn = BSZ;
    if (nn <= 0) return;
    for (int t = tid; t < BSZ * (NCLS + 1); t += 256) ((float*)acc)[t] = 0.f;
    __syncthreads();

    unsigned start = hist[(unsigned)bkt * NCHUNK];
    unsigned end = (bkt == NBKT - 1) ? N_EDGES : hist[(unsigned)(bkt + 1) * NCHUNK];
    int j2 = tid & 3, rr = tid >> 2;        // 64 edge slots x 4 pair-lanes
    int jf = j2 * 2;
    unsigned e = start + (unsigned)(slice * 64 + rr);
    for (; e + 768u < end; e += 1024u) {
        unsigned r0 = rec[e], r1 = rec[e + 256u], r2 = rec[e + 512u], r3 = rec[e + 768u];
        unsigned p0 = hd2b[(size_t)(r0 >> 8) * 4 + j2];
        unsigned p1 = hd2b[(size_t)(r1 >> 8) * 4 + j2];
        unsigned p2 = hd2b[(size_t)(r2 >> 8) * 4 + j2];
        unsigned p3 = hd2b[(size_t)(r3 >> 8) * 4 + j2];
        atomicAdd(&acc[r0 & 255u][jf],     __uint_as_float(p0 << 16));
        atomicAdd(&acc[r0 & 255u][jf + 1], __uint_as_float(p0 & 0xFFFF0000u));
        atomicAdd(&acc[r1 & 255u][jf],     __uint_as_float(p1 << 16));
        atomicAdd(&acc[r1 & 255u][jf + 1], __uint_as_float(p1 & 0xFFFF0000u));
        atomicAdd(&acc[r2 & 255u][jf],     __uint_as_float(p2 << 16));
        atomicAdd(&acc[r2 & 255u][jf + 1], __uint_as_float(p2 & 0xFFFF0000u));
        atomicAdd(&acc[r3 & 255u][jf],     __uint_as_float(p3 << 16));
        atomicAdd(&acc[r3 & 255u][jf + 1], __uint_as_float(p3 & 0xFFFF0000u));
    }
    for (; e < end; e += 256u) {
        unsigned r = rec[e];
        unsigned p = hd2b[(size_t)(r >> 8) * 4 + j2];
        atomicAdd(&acc[r & 255u][jf],     __uint_as_float(p << 16));
        atomicAdd(&acc[r & 255u][jf + 1], __uint_as_float(p & 0xFFFF0000u));
    }
    __syncthreads();
    for (int t = tid; t < nn * NCLS; t += 256) {
        float v = acc[t >> 3][t & 7];
        if (v != 0.f) atomicAdd(&agg2[(size_t)node0 * NCLS + t], v);
    }
}

// epilogue 2: logits = dis*agg2 + b2 -> log_softmax   (dv restored!)
__global__ void k_epi2(const float* __restrict__ agg2, const float* __restrict__ dis,
                       const float* __restrict__ b2, float* __restrict__ out) {
    int i = blockIdx.x * blockDim.x + threadIdx.x;
    if (i >= N_NODES) return;
    float dv = dis[i];
    const float4* ap = (const float4*)(agg2 + (size_t)i * NCLS);
    float4 a0 = ap[0], a1 = ap[1];
    float l[NCLS];
    l[0] = dv * a0.x + b2[0]; l[1] = dv * a0.y + b2[1];
    l[2] = dv * a0.z + b2[2]; l[3] = dv * a0.w + b2[3];
    l[4] = dv * a1.x + b2[4]; l[5] = dv * a1.y + b2[5];
    l[6] = dv * a1.z + b2[6]; l[7] = dv * a1.w + b2[7];
    float m = l[0];
    #pragma unroll
    for (int k = 1; k < NCLS; ++k) m = fmaxf(m, l[k]);
    float ssum = 0.f;
    #pragma unroll
    for (int k = 0; k < NCLS; ++k) ssum += __expf(l[k] - m);
    float lse = logf(ssum) + m;
    float4* op = (float4*)(out + (size_t)i * NCLS);
    op[0] = make_float4(l[0] - lse, l[1] - lse, l[2] - lse, l[3] - lse);
    op[1] = make_float4(l[4] - lse, l[5] - lse, l[6] - lse, l[7] - lse);
}

extern "C" void kernel_launch(void* const* d_in, const int* in_sizes, int n_in,
                              void* d_out, int out_size, void* d_ws, size_t ws_size,
                              hipStream_t stream) {
    const float* x  = (const float*)d_in[0];
    const int*   ei = (const int*)d_in[1];
    const float* W1 = (const float*)d_in[2];
    const float* b1 = (const float*)d_in[3];
    const float* W2 = (const float*)d_in[4];
    const float* b2 = (const float*)d_in[5];
    float* out = (float*)d_out;

    const int* src = ei;
    const int* dst = ei + N_EDGES;

    unsigned* ws = (unsigned*)d_ws;
    const size_t N = N_NODES;
    unsigned* deg  = ws;
    float*    dis  = (float*)(ws + N);
    unsigned* hist = ws + 2 * N;
    unsigned* bsum = hist + TOTH;
    unsigned* rec  = bsum + 1024;
    float*    agg1 = (float*)(rec + N_EDGES);
    unsigned* hd1b = (unsigned*)(agg1 + 16 * N);
    float*    agg2 = (float*)(hd1b + 8 * N);
    unsigned* hd2b = (unsigned*)(agg2 + 8 * N);

    int nbN = (N_NODES + 255) / 256;   // 391

    k_zero_deg<<<nbN, 256, 0, stream>>>(deg);
    k_hist <<<NCHUNK, 256, 0, stream>>>(dst, hist);
    k_scan1<<<NBS1, 256, 0, stream>>>(hist, bsum);
    k_scan2<<<1, 1024, 0, stream>>>(bsum);
    k_scan3<<<NBS1, 256, 0, stream>>>(hist, bsum);
    k_fill <<<NCHUNK, 256, 0, stream>>>(src, dst, hist, rec);
    k_deg  <<<NBKT * NSLICE, 256, 0, stream>>>(hist, rec, deg);
    k_disk <<<nbN, 256, 0, stream>>>(deg, dis);
    k_gemm1<<<(N_NODES + 63) / 64, 256, 0, stream>>>(x, W1, dis, agg1, hd1b);
    k_agg1 <<<NBKT * NSLICE, 256, 0, stream>>>(hist, rec, hd1b, agg1);
    k_epi1 <<<nbN, 256, 0, stream>>>(agg1, dis, b1, W2, agg2, hd2b);
    k_agg2 <<<NBKT * NSLICE, 256, 0, stream>>>(hist, rec, hd2b, agg2);
    k_epi2 <<<nbN, 256, 0, stream>>>(agg2, dis, b2, out);
}